// Round 1
// baseline (477.910 us; speedup 1.0000x reference)
//
#include <hip/hip_runtime.h>

#define NTAG 64
#define SOS_T 61
#define EOS_T 62
#define PAD_T 63
#define BB 512
#define SS 1024

__global__ __launch_bounds__(64) void crf_nll_kernel(
    const float* __restrict__ emissions,  // [B,S,64]
    const int*   __restrict__ tags,       // [B,S]
    const float* __restrict__ mask,       // [B,S]
    const float* __restrict__ trans,      // [64,64]
    float* __restrict__ out)              // [1]
{
    const int b = blockIdx.x;
    const int j = threadIdx.x;            // tag index, lane
    const float LOG2E = 1.4426950408889634f;
    const float LN2   = 0.6931471805599453f;

    __shared__ __align__(16) float A_lds[NTAG];
    __shared__ float T_lds[NTAG * NTAG];

    // Preload transitions: raw copy in LDS (for score lookups),
    // exp(T) column j in registers (for the exp-space matvec).
    float expTcol[NTAG];
#pragma unroll
    for (int i = 0; i < NTAG; ++i) {
        float tv = trans[i * NTAG + j];
        T_lds[i * NTAG + j] = tv;
        expTcol[i] = exp2f(tv * LOG2E);   // exp(tv); -1e6 underflows to exactly 0
    }
    __syncthreads();

    const float* emb = emissions + (size_t)b * SS * NTAG;
    const int*   tgb = tags + (size_t)b * SS;
    const float* mkb = mask + (size_t)b * SS;

    // ---- t = 0 init ----
    float em0  = emb[j];
    int   tag0 = tgb[0];
    float a0   = T_lds[SOS_T * NTAG + j] + em0;       // log-domain alpha0
    float A    = exp2f(a0 * LOG2E);                   // exp-space state, lane j holds tag j
    int   Mint = 0;                                   // alpha[j] = ln(A[j]) + Mint*ln2

    float score_em  = (j == tag0) ? em0 : 0.0f;       // lane-partial emission score
    float score_uni = T_lds[SOS_T * NTAG + tag0];     // uniform (replicated) score part
    float msum      = mkb[0];
    int   prev_tag  = tag0;

    // ---- software-pipelined prefetch (depth 4), named regs (no dyn-indexed arrays) ----
    float em_p0 = emb[1 * NTAG + j];
    float em_p1 = emb[2 * NTAG + j];
    float em_p2 = emb[3 * NTAG + j];
    float em_p3 = emb[4 * NTAG + j];
    int   tg_p0 = tgb[1], tg_p1 = tgb[2], tg_p2 = tgb[3], tg_p3 = tgb[4];
    float mk_p0 = mkb[1], mk_p1 = mkb[2], mk_p2 = mkb[3], mk_p3 = mkb[4];

#pragma unroll 8
    for (int t = 1; t < SS; ++t) {
        float em_t  = em_p0;
        int   tag_t = tg_p0;
        float m_t   = mk_p0;

        // rotate ring + issue prefetch for t+4 (clamped; renamed away by unroll)
        em_p0 = em_p1; em_p1 = em_p2; em_p2 = em_p3;
        tg_p0 = tg_p1; tg_p1 = tg_p2; tg_p2 = tg_p3;
        mk_p0 = mk_p1; mk_p1 = mk_p2; mk_p2 = mk_p3;
        int tn = (t + 4 < SS) ? (t + 4) : (SS - 1);
        em_p3 = emb[tn * NTAG + j];
        tg_p3 = tgb[tn];
        mk_p3 = mkb[tn];

        // broadcast A across the wave
        A_lds[j] = A;
        __syncthreads();

        // q[j] = sum_i A[i] * expT[i][j]   (4 independent FMA chains)
        float q0 = 0.0f, q1 = 0.0f, q2 = 0.0f, q3 = 0.0f;
        const float4* Af = (const float4*)A_lds;
#pragma unroll
        for (int i = 0; i < NTAG / 4; ++i) {
            float4 a4 = Af[i];
            q0 = fmaf(a4.x, expTcol[4 * i + 0], q0);
            q1 = fmaf(a4.y, expTcol[4 * i + 1], q1);
            q2 = fmaf(a4.z, expTcol[4 * i + 2], q2);
            q3 = fmaf(a4.w, expTcol[4 * i + 3], q3);
        }
        float q = (q0 + q1) + (q2 + q3);
        float qn = q * exp2f(em_t * LOG2E);           // fold in emission factor

        bool live = (m_t != 0.0f);                    // uniform branch
        if (live) {
            A = qn;
            score_em += (j == tag_t) ? em_t : 0.0f;
            score_uni += T_lds[prev_tag * NTAG + tag_t];
            msum += m_t;
        }
        prev_tag = tag_t;

        // periodic exact power-of-2 rescale (every 8 steps)
        if ((t & 7) == 7) {
            float r = A;
#pragma unroll
            for (int o = 32; o > 0; o >>= 1) r = fmaxf(r, __shfl_xor(r, o));
            int e = ((__float_as_int(r) >> 23) & 255) - 127;  // ilogb(max)
            A = ldexpf(A, -e);                                // exact, 0 stays 0
            Mint += e;
        }
    }

    // ---- finalize: log_z = ln( sum_j A[j]*exp(T[j][EOS]) ) + Mint*ln2 ----
    float t_eos = T_lds[j * NTAG + EOS_T];
    float val = A * exp2f(t_eos * LOG2E);
#pragma unroll
    for (int o = 32; o > 0; o >>= 1) val += __shfl_xor(val, o);
    float log_z = (log2f(val) + (float)Mint) * LN2;

    // gold-path score
    int   last_idx = (int)(msum + 0.5f) - 1;
    int   last_tag = tgb[last_idx];
    float score = score_uni + T_lds[last_tag * NTAG + EOS_T];
#pragma unroll
    for (int o = 32; o > 0; o >>= 1) score_em += __shfl_xor(score_em, o);
    score += score_em;

    if (j == 0) atomicAdd(out, log_z - score);
}

extern "C" void kernel_launch(void* const* d_in, const int* in_sizes, int n_in,
                              void* d_out, int out_size, void* d_ws, size_t ws_size,
                              hipStream_t stream) {
    const float* emissions = (const float*)d_in[0];
    const int*   tags      = (const int*)d_in[1];
    const float* mask      = (const float*)d_in[2];
    const float* trans     = (const float*)d_in[3];
    float* out = (float*)d_out;

    hipMemsetAsync(out, 0, sizeof(float), stream);
    crf_nll_kernel<<<dim3(BB), dim3(64), 0, stream>>>(emissions, tags, mask, trans, out);
}

// Round 2
// 325.612 us; speedup vs baseline: 1.4677x; 1.4677x over previous
//
#include <hip/hip_runtime.h>

#define NTAG 64
#define SOS_T 61
#define EOS_T 62
#define BB 512
#define SS 1024
#define LOG2E 1.4426950408889634f
#define LN2   0.6931471805599453f

typedef float v2f __attribute__((ext_vector_type(2)));

// One wave (64 lanes) per batch row; lane = tag. Exp-space forward recursion:
// A_new[j] = exp(em[t,j]) * sum_i A[i]*expT[i][j], with exact pow2 rescale
// every 8 steps (exponent bookkeeping in Mint). No barrier in the main loop:
// single-wave block + in-order DS pipe make write->read-all safe.
#define STEP(EF, MK, RESC) do {                                              \
    A_lds[j] = A;                                                            \
    const v2f* Av_ = (const v2f*)A_lds;                                      \
    v2f q0_ = {0.f, 0.f}, q1_ = q0_, q2_ = q0_, q3_ = q0_;                   \
    float mx_ = 0.f;                                                         \
    _Pragma("unroll")                                                        \
    for (int i_ = 0; i_ < 8; ++i_) {                                         \
        v2f a0_ = Av_[4*i_+0];                                               \
        v2f a1_ = Av_[4*i_+1];                                               \
        v2f a2_ = Av_[4*i_+2];                                               \
        v2f a3_ = Av_[4*i_+3];                                               \
        asm("v_pk_fma_f32 %0, %1, %2, %0" : "+v"(q0_) : "v"(a0_), "v"(expT2[4*i_+0])); \
        asm("v_pk_fma_f32 %0, %1, %2, %0" : "+v"(q1_) : "v"(a1_), "v"(expT2[4*i_+1])); \
        asm("v_pk_fma_f32 %0, %1, %2, %0" : "+v"(q2_) : "v"(a2_), "v"(expT2[4*i_+2])); \
        asm("v_pk_fma_f32 %0, %1, %2, %0" : "+v"(q3_) : "v"(a3_), "v"(expT2[4*i_+3])); \
        if (RESC) {                                                          \
            mx_ = fmaxf(mx_, fmaxf(fmaxf(a0_.x, a0_.y), fmaxf(a1_.x, a1_.y))); \
            mx_ = fmaxf(mx_, fmaxf(fmaxf(a2_.x, a2_.y), fmaxf(a3_.x, a3_.y))); \
        }                                                                    \
    }                                                                        \
    v2f qs_ = (q0_ + q1_) + (q2_ + q3_);                                     \
    float qq_ = qs_.x + qs_.y;                                               \
    float An_ = qq_ * (EF);                                                  \
    A = ((MK) != 0.f) ? An_ : A;                                             \
    if (RESC) {                                                              \
        int e_ = ((__float_as_int(mx_) >> 23) & 255) - 127;                  \
        A = ldexpf(A, -e_);                                                  \
        Mint += e_;                                                          \
    }                                                                        \
} while (0)

__global__ __launch_bounds__(64) void crf_nll_kernel(
    const float* __restrict__ emissions,  // [B,S,64]
    const int*   __restrict__ tags,       // [B,S]
    const float* __restrict__ mask,       // [B,S]
    const float* __restrict__ trans,      // [64,64]
    float* __restrict__ out)              // [1]
{
    const int b = blockIdx.x;
    const int j = threadIdx.x;            // tag index = lane

    __shared__ __align__(16) float A_lds[NTAG];
    __shared__ __align__(16) float T_lds[NTAG * NTAG];
    __shared__ __align__(16) float mask_lds[SS];

    // ---- stage transitions: raw copy to LDS (score lookups), exp(T) col j in regs ----
    const float4* tg4 = (const float4*)trans;
    float4* tl4 = (float4*)T_lds;
#pragma unroll
    for (int i = 0; i < 16; ++i) tl4[i * 64 + j] = tg4[i * 64 + j];

    v2f expT2[32];
#pragma unroll
    for (int i = 0; i < 32; ++i) {
        float t0 = trans[(2 * i + 0) * NTAG + j];
        float t1 = trans[(2 * i + 1) * NTAG + j];
        expT2[i].x = exp2f(t0 * LOG2E);   // -1e6 underflows to exactly 0
        expT2[i].y = exp2f(t1 * LOG2E);
    }
    __syncthreads();   // once, prologue only

    const float* emb_g = emissions + (size_t)b * SS * NTAG;
    const int*   tgb   = tags + (size_t)b * SS;
    const float* mkb   = mask + (size_t)b * SS;

    // ---- gold-path score + msum + mask->LDS, lane-parallel over time ----
    float sc = 0.f, ms = 0.f;
#pragma unroll 4
    for (int k = 0; k < SS / 64; ++k) {
        int t = k * 64 + j;
        int tg = tgb[t];
        float m = mkb[t];
        mask_lds[t] = m;
        ms += m;
        float e = emb_g[t * NTAG + tg];
        if (t == 0) {
            sc += T_lds[SOS_T * NTAG + tg] + e;
        } else {
            int tgp = tgb[t - 1];
            sc += m * (e + T_lds[tgp * NTAG + tg]);
        }
    }
#pragma unroll
    for (int o = 32; o > 0; o >>= 1) {
        sc += __shfl_xor(sc, o);
        ms += __shfl_xor(ms, o);
    }
    int last_idx = (int)(ms + 0.5f) - 1;
    int last_tag = tgb[last_idx];
    sc += T_lds[last_tag * NTAG + EOS_T];

    // ---- t=0 init ----
    float A = exp2f((T_lds[SOS_T * NTAG + j] + emb_g[j]) * LOG2E);
    int Mint = 0;

    // ---- em register ring: t = 1..8 ----
    float emr0 = emb_g[1 * NTAG + j];
    float emr1 = emb_g[2 * NTAG + j];
    float emr2 = emb_g[3 * NTAG + j];
    float emr3 = emb_g[4 * NTAG + j];
    float emr4 = emb_g[5 * NTAG + j];
    float emr5 = emb_g[6 * NTAG + j];
    float emr6 = emb_g[7 * NTAG + j];
    float emr7 = emb_g[8 * NTAG + j];

    // ---- main recursion: 127 groups of 8 (t = 1..1016), then 7-step tail ----
#pragma unroll 1
    for (int tb = 1; tb <= SS - 15; tb += 8) {
        float ef0 = exp2f(emr0 * LOG2E);
        float ef1 = exp2f(emr1 * LOG2E);
        float ef2 = exp2f(emr2 * LOG2E);
        float ef3 = exp2f(emr3 * LOG2E);
        float ef4 = exp2f(emr4 * LOG2E);
        float ef5 = exp2f(emr5 * LOG2E);
        float ef6 = exp2f(emr6 * LOG2E);
        float ef7 = exp2f(emr7 * LOG2E);
        float mk0 = mask_lds[tb + 0];
        float mk1 = mask_lds[tb + 1];
        float mk2 = mask_lds[tb + 2];
        float mk3 = mask_lds[tb + 3];
        float mk4 = mask_lds[tb + 4];
        float mk5 = mask_lds[tb + 5];
        float mk6 = mask_lds[tb + 6];
        float mk7 = mask_lds[tb + 7];
        int tn = tb + 8;
        emr0 = emb_g[(tn + 0) * NTAG + j];
        emr1 = emb_g[(tn + 1) * NTAG + j];
        emr2 = emb_g[(tn + 2) * NTAG + j];
        emr3 = emb_g[(tn + 3) * NTAG + j];
        emr4 = emb_g[(tn + 4) * NTAG + j];
        emr5 = emb_g[(tn + 5) * NTAG + j];
        emr6 = emb_g[(tn + 6) * NTAG + j];
        int t7 = (tn + 7 > SS - 1) ? (SS - 1) : (tn + 7);
        emr7 = emb_g[t7 * NTAG + j];

        STEP(ef0, mk0, false);
        STEP(ef1, mk1, false);
        STEP(ef2, mk2, false);
        STEP(ef3, mk3, false);
        STEP(ef4, mk4, false);
        STEP(ef5, mk5, false);
        STEP(ef6, mk6, true);   // rescale once per group
        STEP(ef7, mk7, false);
    }
    {   // tail: t = 1017..1023 (ring holds them already)
        float ef0 = exp2f(emr0 * LOG2E);
        float ef1 = exp2f(emr1 * LOG2E);
        float ef2 = exp2f(emr2 * LOG2E);
        float ef3 = exp2f(emr3 * LOG2E);
        float ef4 = exp2f(emr4 * LOG2E);
        float ef5 = exp2f(emr5 * LOG2E);
        float ef6 = exp2f(emr6 * LOG2E);
        STEP(ef0, mask_lds[SS - 7], false);
        STEP(ef1, mask_lds[SS - 6], false);
        STEP(ef2, mask_lds[SS - 5], true);
        STEP(ef3, mask_lds[SS - 4], false);
        STEP(ef4, mask_lds[SS - 3], false);
        STEP(ef5, mask_lds[SS - 2], false);
        STEP(ef6, mask_lds[SS - 1], false);
    }

    // ---- finalize: log_z = ln( sum_j A[j]*exp(T[j][EOS]) ) + Mint*ln2 ----
    float val = A * exp2f(T_lds[j * NTAG + EOS_T] * LOG2E);
#pragma unroll
    for (int o = 32; o > 0; o >>= 1) val += __shfl_xor(val, o);
    float log_z = (log2f(val) + (float)Mint) * LN2;

    if (j == 0) atomicAdd(out, log_z - sc);
}

extern "C" void kernel_launch(void* const* d_in, const int* in_sizes, int n_in,
                              void* d_out, int out_size, void* d_ws, size_t ws_size,
                              hipStream_t stream) {
    const float* emissions = (const float*)d_in[0];
    const int*   tags      = (const int*)d_in[1];
    const float* mask      = (const float*)d_in[2];
    const float* trans     = (const float*)d_in[3];
    float* out = (float*)d_out;

    hipMemsetAsync(out, 0, sizeof(float), stream);
    crf_nll_kernel<<<dim3(BB), dim3(64), 0, stream>>>(emissions, tags, mask, trans, out);
}

// Round 3
// 264.007 us; speedup vs baseline: 1.8102x; 1.2333x over previous
//
#include <hip/hip_runtime.h>

#define NTAG 64
#define SOS_T 61
#define EOS_T 62
#define BB 512
#define SS 1024
#define LOG2E 1.4426950408889634f
#define LN2   0.6931471805599453f

// One wave per batch row; lane = tag. Exp-space forward recursion.
// Broadcast of A across lanes via v_readlane -> SGPRs (no LDS on the
// critical path); dot via v_fmac with SGPR operand; exact pow2 rescale
// every 8 steps done with scalar integer max on the readlane bits.
#define STEP(EF, MK, RESC) do {                                              \
    float q0_=0.f,q1_=0.f,q2_=0.f,q3_=0.f,q4_=0.f,q5_=0.f,q6_=0.f,q7_=0.f;   \
    unsigned mxu_ = 0u;                                                      \
    _Pragma("unroll")                                                        \
    for (int i_ = 0; i_ < 64; ++i_) {                                        \
        unsigned ab_ = (unsigned)__builtin_amdgcn_readlane(                  \
                            (int)__float_as_uint(A), i_);                    \
        float av_ = __uint_as_float(ab_);                                    \
        switch (i_ & 7) {                                                    \
            case 0: q0_ = fmaf(av_, eT[i_], q0_); break;                     \
            case 1: q1_ = fmaf(av_, eT[i_], q1_); break;                     \
            case 2: q2_ = fmaf(av_, eT[i_], q2_); break;                     \
            case 3: q3_ = fmaf(av_, eT[i_], q3_); break;                     \
            case 4: q4_ = fmaf(av_, eT[i_], q4_); break;                     \
            case 5: q5_ = fmaf(av_, eT[i_], q5_); break;                     \
            case 6: q6_ = fmaf(av_, eT[i_], q6_); break;                     \
            default: q7_ = fmaf(av_, eT[i_], q7_); break;                    \
        }                                                                    \
        if (RESC) mxu_ = (ab_ > mxu_) ? ab_ : mxu_;                          \
    }                                                                        \
    float qq_ = ((q0_+q1_)+(q2_+q3_)) + ((q4_+q5_)+(q6_+q7_));               \
    float An_ = qq_ * (EF);                                                  \
    A = ((MK) != 0.f) ? An_ : A;                                             \
    if (RESC) {                                                              \
        int e_ = (int)(mxu_ >> 23) - 127;                                    \
        e_ = (mxu_ == 0u) ? 0 : e_;                                          \
        float sc_ = __uint_as_float((unsigned)(127 - e_) << 23);             \
        A *= sc_;                                                            \
        Mint += e_;                                                          \
    }                                                                        \
} while (0)

__global__ __launch_bounds__(64) void crf_nll_kernel(
    const float* __restrict__ emissions,  // [B,S,64]
    const int*   __restrict__ tags,       // [B,S]
    const float* __restrict__ mask,       // [B,S]
    const float* __restrict__ trans,      // [64,64]
    float* __restrict__ out)              // [1]
{
    const int b = blockIdx.x;
    const int j = threadIdx.x;            // tag index = lane

    __shared__ __align__(16) float T_lds[NTAG * NTAG];
    __shared__ __align__(16) float mask_lds[SS];

    // ---- stage transitions: raw copy to LDS (score lookups), exp(T) col j in regs ----
    const float4* tg4 = (const float4*)trans;
    float4* tl4 = (float4*)T_lds;
#pragma unroll
    for (int i = 0; i < 16; ++i) tl4[i * 64 + j] = tg4[i * 64 + j];

    float eT[NTAG];
#pragma unroll
    for (int i = 0; i < NTAG; ++i)
        eT[i] = exp2f(trans[i * NTAG + j] * LOG2E);   // -1e6 underflows to 0
    __syncthreads();   // once, prologue only

    const float* emb_g = emissions + (size_t)b * SS * NTAG;
    const int*   tgb   = tags + (size_t)b * SS;
    const float* mkb   = mask + (size_t)b * SS;

    // ---- gold-path score + msum + mask->LDS, lane-parallel over time ----
    float sc = 0.f, ms = 0.f;
#pragma unroll 4
    for (int k = 0; k < SS / 64; ++k) {
        int t = k * 64 + j;
        int tg = tgb[t];
        float m = mkb[t];
        mask_lds[t] = m;
        ms += m;
        float e = emb_g[t * NTAG + tg];
        if (t == 0) {
            sc += T_lds[SOS_T * NTAG + tg] + e;
        } else {
            int tgp = tgb[t - 1];
            sc += m * (e + T_lds[tgp * NTAG + tg]);
        }
    }
#pragma unroll
    for (int o = 32; o > 0; o >>= 1) {
        sc += __shfl_xor(sc, o);
        ms += __shfl_xor(ms, o);
    }
    int last_idx = (int)(ms + 0.5f) - 1;
    int last_tag = tgb[last_idx];
    sc += T_lds[last_tag * NTAG + EOS_T];

    // ---- t=0 init ----
    float A = exp2f((T_lds[SOS_T * NTAG + j] + emb_g[j]) * LOG2E);
    int Mint = 0;

    // ---- em prefetch ring, depth 16: holds t = tb..tb+15 ----
    float er[16];
#pragma unroll
    for (int k = 0; k < 16; ++k) er[k] = emb_g[(1 + k) * NTAG + j];

    // ---- main recursion: 63 groups of 16 (t = 1..1008), then 15-step tail ----
#pragma unroll 1
    for (int tb = 1; tb <= SS - 31; tb += 16) {
        float ef[16];
#pragma unroll
        for (int k = 0; k < 16; ++k) ef[k] = exp2f(er[k] * LOG2E);
#pragma unroll
        for (int k = 0; k < 16; ++k) {
            int tn = tb + 16 + k;
            tn = (tn > SS - 1) ? (SS - 1) : tn;
            er[k] = emb_g[tn * NTAG + j];
        }
        float mk[16];
#pragma unroll
        for (int k = 0; k < 16; ++k) mk[k] = mask_lds[tb + k];

        STEP(ef[0],  mk[0],  false);
        STEP(ef[1],  mk[1],  false);
        STEP(ef[2],  mk[2],  false);
        STEP(ef[3],  mk[3],  false);
        STEP(ef[4],  mk[4],  false);
        STEP(ef[5],  mk[5],  false);
        STEP(ef[6],  mk[6],  false);
        STEP(ef[7],  mk[7],  true);
        STEP(ef[8],  mk[8],  false);
        STEP(ef[9],  mk[9],  false);
        STEP(ef[10], mk[10], false);
        STEP(ef[11], mk[11], false);
        STEP(ef[12], mk[12], false);
        STEP(ef[13], mk[13], false);
        STEP(ef[14], mk[14], false);
        STEP(ef[15], mk[15], true);
    }
    {   // tail: t = 1009..1023 (15 steps, ring holds them)
        float ef[15];
#pragma unroll
        for (int k = 0; k < 15; ++k) ef[k] = exp2f(er[k] * LOG2E);
        float mk[15];
#pragma unroll
        for (int k = 0; k < 15; ++k) mk[k] = mask_lds[SS - 15 + k];

        STEP(ef[0],  mk[0],  false);
        STEP(ef[1],  mk[1],  false);
        STEP(ef[2],  mk[2],  false);
        STEP(ef[3],  mk[3],  false);
        STEP(ef[4],  mk[4],  false);
        STEP(ef[5],  mk[5],  false);
        STEP(ef[6],  mk[6],  false);
        STEP(ef[7],  mk[7],  true);
        STEP(ef[8],  mk[8],  false);
        STEP(ef[9],  mk[9],  false);
        STEP(ef[10], mk[10], false);
        STEP(ef[11], mk[11], false);
        STEP(ef[12], mk[12], false);
        STEP(ef[13], mk[13], false);
        STEP(ef[14], mk[14], false);
    }

    // ---- finalize: log_z = ln( sum_j A[j]*exp(T[j][EOS]) ) + Mint*ln2 ----
    float val = A * exp2f(T_lds[j * NTAG + EOS_T] * LOG2E);
#pragma unroll
    for (int o = 32; o > 0; o >>= 1) val += __shfl_xor(val, o);
    float log_z = (log2f(val) + (float)Mint) * LN2;

    if (j == 0) atomicAdd(out, log_z - sc);
}

extern "C" void kernel_launch(void* const* d_in, const int* in_sizes, int n_in,
                              void* d_out, int out_size, void* d_ws, size_t ws_size,
                              hipStream_t stream) {
    const float* emissions = (const float*)d_in[0];
    const int*   tags      = (const int*)d_in[1];
    const float* mask      = (const float*)d_in[2];
    const float* trans     = (const float*)d_in[3];
    float* out = (float*)d_out;

    hipMemsetAsync(out, 0, sizeof(float), stream);
    crf_nll_kernel<<<dim3(BB), dim3(64), 0, stream>>>(emissions, tags, mask, trans, out);
}